// Round 2
// baseline (35824.597 us; speedup 1.0000x reference)
//
#include <hip/hip_runtime.h>
#include <hip/hip_bf16.h>
#include <cstdint>
#include <cstddef>

#define N_NODES 30000
#define T_STEPS 12
#define E_EDGES 480000
#define F_IN 128
#define H1 256
#define H2 128
#define RAWF 20
#define HID 256
#define GATES 1024
#define OUTF 64

__device__ __forceinline__ float sigmoidf_(float x) { return 1.0f / (1.0f + __expf(-x)); }

// ---------------------------------------------------------------------------
// Generic tiled fp32 GEMM.
//   C[M,NC] = act( A_cat[M,K] * B + bias )
//   A_cat = horizontal concat of up to 3 row-major sources (ld0/ld1/ld2).
//   BT=false: B is [K,NC] row-major.  BT=true: B is [NC,K] row-major (A@B^T).
// Tile 64x64, BK=16, 256 threads, 4x4 per-thread register tile.
// Segment widths/boundaries must be multiples of 4 (128/20/256 -> 128,148: ok).
// ---------------------------------------------------------------------------
template <bool BT>
__global__ __launch_bounds__(256) void gemm_tile(
    const float* __restrict__ A0, int ld0, int K0,
    const float* __restrict__ A1, int ld1, int K1,
    const float* __restrict__ A2, int ld2, int K2,
    const float* __restrict__ Bm, int ldb,
    float* __restrict__ C, int ldc, int M,
    const float* __restrict__ bias, int act)
{
    const int K = K0 + K1 + K2;
    __shared__ float As[16][68];   // [k][m], +4 pad
    __shared__ float Bs[16][68];   // [k][n], +4 pad

    const int tid = threadIdx.x;
    const int tx = tid & 15;
    const int ty = tid >> 4;
    const int m_blk = blockIdx.x * 64;
    const int n_blk = blockIdx.y * 64;

    // loader mapping: 256 threads -> 64 rows x 4 k-chunks (float4 along k)
    const int lm  = tid >> 2;         // 0..63
    const int lk4 = (tid & 3) * 4;    // 0,4,8,12

    float acc[4][4] = {};

    for (int k0t = 0; k0t < K; k0t += 16) {
        // ---- A tile ----
        {
            int gk  = k0t + lk4;
            int row = m_blk + lm;
            if (row >= M) row = M - 1;            // clamp: load valid, write guarded
            float4 v = make_float4(0.f, 0.f, 0.f, 0.f);
            if (gk < K0)            v = *(const float4*)(A0 + (size_t)row * ld0 + gk);
            else if (gk < K0 + K1)  v = *(const float4*)(A1 + (size_t)row * ld1 + (gk - K0));
            else if (gk < K)        v = *(const float4*)(A2 + (size_t)row * ld2 + (gk - K0 - K1));
            As[lk4 + 0][lm] = v.x; As[lk4 + 1][lm] = v.y;
            As[lk4 + 2][lm] = v.z; As[lk4 + 3][lm] = v.w;
        }
        // ---- B tile ----
        if (BT) {
            int gk = k0t + lk4;
            int n  = n_blk + lm;
            float4 v = make_float4(0.f, 0.f, 0.f, 0.f);
            if (gk < K) v = *(const float4*)(Bm + (size_t)n * ldb + gk);
            Bs[lk4 + 0][lm] = v.x; Bs[lk4 + 1][lm] = v.y;
            Bs[lk4 + 2][lm] = v.z; Bs[lk4 + 3][lm] = v.w;
        } else {
            int lk  = tid >> 4;           // 0..15
            int ln4 = (tid & 15) * 4;     // 0..60
            int gk  = k0t + lk;
            float4 v = make_float4(0.f, 0.f, 0.f, 0.f);
            if (gk < K) v = *(const float4*)(Bm + (size_t)gk * ldb + n_blk + ln4);
            *(float4*)&Bs[lk][ln4] = v;
        }
        __syncthreads();

        #pragma unroll
        for (int k = 0; k < 16; ++k) {
            float4 a = *(const float4*)&As[k][ty * 4];
            float4 b = *(const float4*)&Bs[k][tx * 4];
            acc[0][0] += a.x * b.x; acc[0][1] += a.x * b.y; acc[0][2] += a.x * b.z; acc[0][3] += a.x * b.w;
            acc[1][0] += a.y * b.x; acc[1][1] += a.y * b.y; acc[1][2] += a.y * b.z; acc[1][3] += a.y * b.w;
            acc[2][0] += a.z * b.x; acc[2][1] += a.z * b.y; acc[2][2] += a.z * b.z; acc[2][3] += a.z * b.w;
            acc[3][0] += a.w * b.x; acc[3][1] += a.w * b.y; acc[3][2] += a.w * b.z; acc[3][3] += a.w * b.w;
        }
        __syncthreads();
    }

    #pragma unroll
    for (int i = 0; i < 4; ++i) {
        int row = m_blk + ty * 4 + i;
        if (row < M) {
            #pragma unroll
            for (int j = 0; j < 4; ++j) {
                int col = n_blk + tx * 4 + j;
                float v = acc[i][j];
                if (bias) v += bias[col];
                if (act)  v = fmaxf(v, 0.f);
                C[(size_t)row * ldc + col] = v;
            }
        }
    }
}

// ---------------------------------------------------------------------------
// Per-timestep spmm: out[row] += w * sup[col] over E edges; one wave per edge.
// ---------------------------------------------------------------------------
__global__ __launch_bounds__(256) void spmm_h256(
    const int* __restrict__ erow, const int* __restrict__ ecol,
    const float* __restrict__ ew, const float* __restrict__ sup,
    float* __restrict__ out)
{
    int gid  = blockIdx.x * 256 + threadIdx.x;
    int e    = gid >> 6;
    int lane = gid & 63;
    if (e >= E_EDGES) return;
    int r = erow[e], c = ecol[e];
    float w = ew[e];
    const float4 v = *(const float4*)(sup + (size_t)c * 256 + lane * 4);
    float* o = out + (size_t)r * 256 + lane * 4;
    unsafeAtomicAdd(o + 0, v.x * w);
    unsafeAtomicAdd(o + 1, v.y * w);
    unsafeAtomicAdd(o + 2, v.z * w);
    unsafeAtomicAdd(o + 3, v.w * w);
}

__global__ __launch_bounds__(256) void spmm_h128(
    const int* __restrict__ erow, const int* __restrict__ ecol,
    const float* __restrict__ ew, const float* __restrict__ sup,
    float* __restrict__ out)
{
    int gid  = blockIdx.x * 256 + threadIdx.x;
    int e    = gid >> 6;
    int lane = gid & 63;
    if (e >= E_EDGES) return;
    int r = erow[e], c = ecol[e];
    float w = ew[e];
    const float2 v = *(const float2*)(sup + (size_t)c * 128 + lane * 2);
    float* o = out + (size_t)r * 128 + lane * 2;
    unsafeAtomicAdd(o + 0, v.x * w);
    unsafeAtomicAdd(o + 1, v.y * w);
}

// X (float4 view, n4 elements) += broadcast bias (cols4 float4s per row), opt relu
__global__ __launch_bounds__(256) void bias_act(
    float4* __restrict__ X, const float* __restrict__ b, int n4, int cols4, int act)
{
    for (int i = blockIdx.x * 256 + threadIdx.x; i < n4; i += gridDim.x * 256) {
        float4 v = X[i];
        const float4 bb = *(const float4*)(b + ((i & (cols4 - 1)) << 2));
        v.x += bb.x; v.y += bb.y; v.z += bb.z; v.w += bb.w;
        if (act) {
            v.x = fmaxf(v.x, 0.f); v.y = fmaxf(v.y, 0.f);
            v.z = fmaxf(v.z, 0.f); v.w = fmaxf(v.w, 0.f);
        }
        X[i] = v;
    }
}

// LSTM cell: gates G[n][1024] (i,f,g,o), c in-place, h out. first => c_prev = 0
__global__ __launch_bounds__(256) void lstm_cell(
    const float* __restrict__ G, float* __restrict__ c,
    float* __restrict__ hout, int first)
{
    int n  = blockIdx.x;
    int hh = threadIdx.x;
    const float* g = G + (size_t)n * GATES;
    float ig = sigmoidf_(g[hh]);
    float fg = sigmoidf_(g[hh + 256]);
    float gg = tanhf(g[hh + 512]);
    float og = sigmoidf_(g[hh + 768]);
    size_t idx = (size_t)n * HID + hh;
    float cp = first ? 0.f : c[idx];
    float cn = fg * cp + ig * gg;
    c[idx] = cn;
    hout[idx] = og * tanhf(cn);
}

// attention pooling over T: block per node, thread per hidden unit
__global__ __launch_bounds__(256) void attn_pool(
    const float* __restrict__ h1, const float* __restrict__ attw,
    const float* __restrict__ attb, float* __restrict__ pooled)
{
    int n  = blockIdx.x;
    int hh = threadIdx.x;
    float hv[T_STEPS];
    float aw = attw[hh];
    __shared__ float red[4][T_STEPS];
    __shared__ float sc[T_STEPS];
    #pragma unroll
    for (int t = 0; t < T_STEPS; ++t) {
        hv[t] = h1[((size_t)t * N_NODES + n) * HID + hh];
        float v = hv[t] * aw;
        #pragma unroll
        for (int off = 32; off; off >>= 1) v += __shfl_down(v, off, 64);
        if ((hh & 63) == 0) red[hh >> 6][t] = v;
    }
    __syncthreads();
    if (hh < T_STEPS)
        sc[hh] = red[0][hh] + red[1][hh] + red[2][hh] + red[3][hh] + attb[0];
    __syncthreads();
    float m = -1e30f;
    #pragma unroll
    for (int t = 0; t < T_STEPS; ++t) m = fmaxf(m, sc[t]);
    float a[T_STEPS], s = 0.f;
    #pragma unroll
    for (int t = 0; t < T_STEPS; ++t) { a[t] = __expf(sc[t] - m); s += a[t]; }
    float inv = 1.f / s;
    float accv = 0.f;
    #pragma unroll
    for (int t = 0; t < T_STEPS; ++t) accv += a[t] * inv * hv[t];
    pooled[(size_t)n * HID + hh] = accv;
}

// pack Wcat0 = [Wih0 | Whh0] (1024 x 404), Wcat1 = [Wih1 | Whh1] (1024 x 512),
// combined biases bc = bih + bhh
__global__ __launch_bounds__(256) void pack_weights(
    const float* __restrict__ Wih0, const float* __restrict__ Whh0,
    const float* __restrict__ bih0, const float* __restrict__ bhh0,
    const float* __restrict__ Wih1, const float* __restrict__ Whh1,
    const float* __restrict__ bih1, const float* __restrict__ bhh1,
    float* __restrict__ Wc0, float* __restrict__ Wc1,
    float* __restrict__ bc0, float* __restrict__ bc1)
{
    int stride = gridDim.x * 256;
    int idx = blockIdx.x * 256 + threadIdx.x;
    for (int i = idx; i < 1024 * 404; i += stride) {
        int g = i / 404, k = i - g * 404;
        Wc0[i] = (k < 148) ? Wih0[g * 148 + k] : Whh0[g * 256 + (k - 148)];
    }
    for (int i = idx; i < 1024 * 512; i += stride) {
        int g = i >> 9, k = i & 511;
        Wc1[i] = (k < 256) ? Wih1[(g << 8) + k] : Whh1[(g << 8) + (k - 256)];
    }
    for (int i = idx; i < 1024; i += stride) {
        bc0[i] = bih0[i] + bhh0[i];
        bc1[i] = bih1[i] + bhh1[i];
    }
}

extern "C" void kernel_launch(void* const* d_in, const int* in_sizes, int n_in,
                              void* d_out, int out_size, void* d_ws, size_t ws_size,
                              hipStream_t stream)
{
    const float* nodes = (const float*)d_in[0];
    const int*   erow  = (const int*)d_in[1];
    const int*   ecol  = (const int*)d_in[2];
    const float* ew    = (const float*)d_in[3];
    const float* raw   = (const float*)d_in[4];
    const float* W1    = (const float*)d_in[5];
    const float* b1    = (const float*)d_in[6];
    const float* W2    = (const float*)d_in[7];
    const float* b2    = (const float*)d_in[8];
    const float* Wih0  = (const float*)d_in[9];
    const float* Whh0  = (const float*)d_in[10];
    const float* bih0  = (const float*)d_in[11];
    const float* bhh0  = (const float*)d_in[12];
    const float* Wih1  = (const float*)d_in[13];
    const float* Whh1  = (const float*)d_in[14];
    const float* bih1  = (const float*)d_in[15];
    const float* bhh1  = (const float*)d_in[16];
    const float* att_w = (const float*)d_in[17];
    const float* att_b = (const float*)d_in[18];
    const float* fcn_w = (const float*)d_in[19];
    const float* fcn_b = (const float*)d_in[20];
    const float* out_w = (const float*)d_in[21];
    const float* out_b = (const float*)d_in[22];
    float* out = (float*)d_out;

    // ---- workspace layout: 177,580,032 floats = ~677 MiB (was 1.079 GB) ----
    float* ws    = (float*)d_ws;
    float* h1seq = ws;                       // 92,160,000 : [T,N,256] for attention
    float* G     = h1seq + 92160000;         // 30,720,000 : gates [N,1024]; reused: pooled,Z
    float* sup1  = G     + 30720000;         //  7,680,000 : [N,256]
    float* xbuf  = sup1  + 7680000;          //  7,680,000 : [N,256]
    float* sup2  = xbuf  + 7680000;          //  3,840,000 : [N,128]
    float* embed = sup2  + 3840000;          //  3,840,000 : [N,128]
    float* h0a   = embed + 3840000;          //  7,680,000 : h0 ping
    float* h0b   = h0a   + 7680000;          //  7,680,000 : h0 pong
    float* c0    = h0b   + 7680000;          //  7,680,000
    float* c1    = c0    + 7680000;          //  7,680,000
    float* Wc0   = c1    + 7680000;          //    413,696
    float* Wc1   = Wc0   + 413696;           //    524,288
    float* bc0   = Wc1   + 524288;           //      1,024
    float* bc1   = bc0   + 1024;             //      1,024
    float* pooled = G;                       // [N,256] reuse
    float* Z      = G + 7680000;             // [N,128] reuse

    dim3 blk(256);

    pack_weights<<<512, blk, 0, stream>>>(Wih0, Whh0, bih0, bhh0,
                                          Wih1, Whh1, bih1, bhh1,
                                          Wc0, Wc1, bc0, bc1);

    for (int t = 0; t < T_STEPS; ++t) {
        const float* nodes_t = nodes + (size_t)t * N_NODES * F_IN;
        const float* raw_t   = raw   + (size_t)t * N_NODES * RAWF;
        const int*   erow_t  = erow  + (size_t)t * E_EDGES;
        const int*   ecol_t  = ecol  + (size_t)t * E_EDGES;
        const float* ew_t    = ew    + (size_t)t * E_EDGES;
        float* h0_cur  = (t & 1) ? h0b : h0a;
        float* h0_prev = (t & 1) ? h0a : h0b;
        float* h1_cur  = h1seq + (size_t)t * N_NODES * HID;
        float* h1_prev = h1seq + (size_t)(t - 1) * N_NODES * HID;

        // sup1 = nodes_t @ W1 : [30000,128]@[128,256]
        gemm_tile<false><<<dim3(469, 4), blk, 0, stream>>>(
            nodes_t, 128, 128, nullptr, 0, 0, nullptr, 0, 0,
            W1, 256, sup1, 256, N_NODES, nullptr, 0);

        hipMemsetAsync(xbuf, 0, (size_t)7680000 * 4, stream);
        spmm_h256<<<dim3(120000), blk, 0, stream>>>(erow_t, ecol_t, ew_t, sup1, xbuf);
        bias_act<<<2048, blk, 0, stream>>>((float4*)xbuf, b1, 1920000, 64, 1);

        // sup2 = x @ W2 : [30000,256]@[256,128]
        gemm_tile<false><<<dim3(469, 2), blk, 0, stream>>>(
            xbuf, 256, 256, nullptr, 0, 0, nullptr, 0, 0,
            W2, 128, sup2, 128, N_NODES, nullptr, 0);

        hipMemsetAsync(embed, 0, (size_t)3840000 * 4, stream);
        spmm_h128<<<dim3(120000), blk, 0, stream>>>(erow_t, ecol_t, ew_t, sup2, embed);
        bias_act<<<2048, blk, 0, stream>>>((float4*)embed, b2, 960000, 32, 0);

        // layer-0 gates = [embed | raw_t | h0_prev] @ Wc0^T + bc0
        gemm_tile<true><<<dim3(469, 16), blk, 0, stream>>>(
            embed, H2, H2,
            raw_t, RAWF, RAWF,
            (t > 0) ? h0_prev : nullptr, HID, (t > 0) ? HID : 0,
            Wc0, 404, G, GATES, N_NODES, bc0, 0);
        lstm_cell<<<N_NODES, blk, 0, stream>>>(G, c0, h0_cur, t == 0);

        // layer-1 gates = [h0_cur | h1_prev] @ Wc1^T + bc1
        gemm_tile<true><<<dim3(469, 16), blk, 0, stream>>>(
            h0_cur, HID, HID,
            (t > 0) ? h1_prev : nullptr, HID, (t > 0) ? HID : 0,
            nullptr, 0, 0,
            Wc1, 512, G, GATES, N_NODES, bc1, 0);
        lstm_cell<<<N_NODES, blk, 0, stream>>>(G, c1, h1_cur, t == 0);
    }

    attn_pool<<<N_NODES, blk, 0, stream>>>(h1seq, att_w, att_b, pooled);

    // z = relu(pooled @ fcn_w + fcn_b) : [30000,256]@[256,128]
    gemm_tile<false><<<dim3(469, 2), blk, 0, stream>>>(
        pooled, 256, 256, nullptr, 0, 0, nullptr, 0, 0,
        fcn_w, 128, Z, 128, N_NODES, fcn_b, 1);
    // out = z @ out_w + out_b : [30000,128]@[128,64]
    gemm_tile<false><<<dim3(469, 1), blk, 0, stream>>>(
        Z, 128, 128, nullptr, 0, 0, nullptr, 0, 0,
        out_w, 64, out, 64, N_NODES, out_b, 0);
}